// Round 1
// 12852.406 us; speedup vs baseline: 1.0374x; 1.0374x over previous
//
#include <hip/hip_runtime.h>
#include <hip/hip_bf16.h>

// Problem: S=48, T=32, B=64, H=1024, E=512, V=32000, PAD=1
// 3H=3072, 2H=2048, 2H+E=2560, 3H+E=3584, decoder steps = T-1 = 31
// R1 changes vs baseline (13332 us):
//  - persistent cooperative encoder GRU (144 dispatches -> 1, spin grid barrier)
//  - decoder: [Wh_d ; W_attn_h] concat GEMM fuses ghdp+dpp (5 -> 4 kernels/step)
//  - output projection: m-tile-major grid so W_out n-panels are reused from L2

using bf16x8 = __attribute__((ext_vector_type(8))) short;
using f32x4  = __attribute__((ext_vector_type(4))) float;
typedef __hip_bfloat16 bf16;

#define SS 48
#define TT 32
#define BB 64
#define HH 1024
#define EE 512
#define VV 32000
#define NBLK_E 256

__device__ __forceinline__ short f2bs(float x) {
  return __builtin_bit_cast(short, __float2bfloat16(x));
}
__device__ __forceinline__ float sigmoidf_(float x) { return 1.f / (1.f + expf(-x)); }

// ---------------------------------------------------------------------------
// Embedding gather + fp32->bf16
// ---------------------------------------------------------------------------
__global__ __launch_bounds__(256) void embed_src(
    const int* __restrict__ src, const float* __restrict__ emb_enc,
    bf16* __restrict__ emb_bf)
{
  int f = blockIdx.x * 256 + threadIdx.x;   // 196608 frags of 8
  int row = f >> 6;                          // E/8 = 64 frags per row
  int e8 = (f & 63) * 8;
  int tok = src[row];
  const float* p = emb_enc + (size_t)tok * EE + e8;
  float4 a = *(const float4*)p;
  float4 b = *(const float4*)(p + 4);
  bf16x8 v;
  v[0] = f2bs(a.x); v[1] = f2bs(a.y); v[2] = f2bs(a.z); v[3] = f2bs(a.w);
  v[4] = f2bs(b.x); v[5] = f2bs(b.y); v[6] = f2bs(b.z); v[7] = f2bs(b.w);
  *(bf16x8*)((short*)emb_bf + (size_t)row * EE + e8) = v;
}

// ---------------------------------------------------------------------------
// MFMA bf16 GEMM:  C[M,N] = A[M,K](bf16) @ W[N,K](fp32->bf16)^T (+bias fp32)
// 128x128 tile. Grid: blockIdx.x = m-tile (fast), blockIdx.y = n-tile (slow)
// so consecutive blocks share the same W n-panel (L2 reuse for huge W_out).
// ---------------------------------------------------------------------------
__global__ __launch_bounds__(256) void gemm_mfma(
    const bf16* __restrict__ A, int lda,
    const float* __restrict__ W, int ldw,
    const float* __restrict__ bias,
    float* __restrict__ C, int ldc,
    int K, int Mstore)
{
  __shared__ __align__(16) short sA[128 * 40];
  __shared__ __align__(16) short sB[128 * 40];
  const int tid = threadIdx.x;
  const int m0 = blockIdx.x * 128;   // m fast: 16 consecutive blocks share W panel
  const int n0 = blockIdx.y * 128;
  const int lane = tid & 63;
  const int wave = tid >> 6;
  const int wr = wave >> 1, wc = wave & 1;
  const int quad = lane >> 4, l15 = lane & 15;

  f32x4 acc[4][4];
#pragma unroll
  for (int i = 0; i < 4; i++)
#pragma unroll
    for (int j = 0; j < 4; j++) acc[i][j] = f32x4{0.f, 0.f, 0.f, 0.f};

  const short* Ag = (const short*)A;

  for (int k0 = 0; k0 < K; k0 += 32) {
#pragma unroll
    for (int f = 0; f < 2; f++) {
      int idx = tid + f * 256;          // 0..511 slots (128 rows x 4 col-groups)
      int r = idx >> 2, cg = idx & 3;
      bf16x8 va = *(const bf16x8*)(Ag + (size_t)(m0 + r) * lda + k0 + cg * 8);
      *(bf16x8*)&sA[r * 40 + cg * 8] = va;
      const float* wp = W + (size_t)(n0 + r) * ldw + k0 + cg * 8;
      float4 w0 = *(const float4*)wp;
      float4 w1 = *(const float4*)(wp + 4);
      bf16x8 vb;
      vb[0] = f2bs(w0.x); vb[1] = f2bs(w0.y); vb[2] = f2bs(w0.z); vb[3] = f2bs(w0.w);
      vb[4] = f2bs(w1.x); vb[5] = f2bs(w1.y); vb[6] = f2bs(w1.z); vb[7] = f2bs(w1.w);
      *(bf16x8*)&sB[r * 40 + cg * 8] = vb;
    }
    __syncthreads();
    bf16x8 af[4], bfr[4];
#pragma unroll
    for (int i = 0; i < 4; i++)
      af[i] = *(const bf16x8*)&sA[(wr * 64 + i * 16 + l15) * 40 + quad * 8];
#pragma unroll
    for (int j = 0; j < 4; j++)
      bfr[j] = *(const bf16x8*)&sB[(wc * 64 + j * 16 + l15) * 40 + quad * 8];
#pragma unroll
    for (int i = 0; i < 4; i++)
#pragma unroll
      for (int j = 0; j < 4; j++)
        acc[i][j] = __builtin_amdgcn_mfma_f32_16x16x32_bf16(af[i], bfr[j], acc[i][j], 0, 0, 0);
    __syncthreads();
  }

#pragma unroll
  for (int i = 0; i < 4; i++) {
#pragma unroll
    for (int j = 0; j < 4; j++) {
#pragma unroll
      for (int r = 0; r < 4; r++) {
        int m = m0 + wr * 64 + i * 16 + quad * 4 + r;
        int n = n0 + wc * 64 + j * 16 + l15;
        if (m < Mstore) {
          float v = acc[i][j][r];
          if (bias) v += bias[n];
          C[(size_t)m * ldc + n] = v;
        }
      }
    }
  }
}

// ---------------------------------------------------------------------------
// fp32 tiled GEMM (64x64 tile, 4x4 micro, K-chunk 16) with split-K support.
// ---------------------------------------------------------------------------
__global__ __launch_bounds__(256) void gemm64(
    const float* __restrict__ A, int lda,
    const float* __restrict__ W, int ldw,
    const float* __restrict__ bias,
    float* __restrict__ C, long long csplit, int ldc,
    int M, int Klen)
{
  __shared__ __align__(16) float As[64][20];
  __shared__ __align__(16) float Ws[64][20];
  const int tid = threadIdx.x;
  const int tx = tid & 15, ty = tid >> 4;
  const int n0 = blockIdx.x * 64;
  const int m0 = blockIdx.y * 64;
  const int kbeg = blockIdx.z * Klen;
  float acc[4][4] = {};

  for (int k0 = kbeg; k0 < kbeg + Klen; k0 += 16) {
#pragma unroll
    for (int i = 0; i < 4; i++) {
      int idx = tid + i * 256;          // 0..1023 : 64 rows x 16 cols
      int r = idx >> 4, c = idx & 15;
      int m = m0 + r;
      As[r][c] = (m < M) ? A[(size_t)m * lda + k0 + c] : 0.f;
      Ws[r][c] = W[(size_t)(n0 + r) * ldw + k0 + c];
    }
    __syncthreads();
#pragma unroll
    for (int kk = 0; kk < 16; kk += 4) {
      float4 a4[4], w4[4];
#pragma unroll
      for (int i = 0; i < 4; i++) a4[i] = *(const float4*)&As[ty + 16 * i][kk];
#pragma unroll
      for (int j = 0; j < 4; j++) w4[j] = *(const float4*)&Ws[tx + 16 * j][kk];
#pragma unroll
      for (int i = 0; i < 4; i++)
#pragma unroll
        for (int j = 0; j < 4; j++) {
          acc[i][j] += a4[i].x * w4[j].x;
          acc[i][j] += a4[i].y * w4[j].y;
          acc[i][j] += a4[i].z * w4[j].z;
          acc[i][j] += a4[i].w * w4[j].w;
        }
    }
    __syncthreads();
  }

  float* Cp = C + (size_t)blockIdx.z * csplit;
#pragma unroll
  for (int i = 0; i < 4; i++) {
    int m = m0 + ty + 16 * i;
    if (m >= M) continue;
#pragma unroll
    for (int j = 0; j < 4; j++) {
      int n = n0 + tx + 16 * j;
      float v = acc[i][j];
      if (bias) v += bias[n];
      Cp[(size_t)m * ldc + n] = v;
    }
  }
}

// ---------------------------------------------------------------------------
// Device-scope spin grid barrier (256 co-resident blocks; monotone counter,
// reset by memset each launch). threadfence = agent acq/rel for cross-XCD.
// ---------------------------------------------------------------------------
__device__ __forceinline__ void gbar(int* bar, int target) {
  __syncthreads();
  if (threadIdx.x == 0) {
    __threadfence();   // release: publish this block's global writes
    __hip_atomic_fetch_add(bar, 1, __ATOMIC_RELAXED, __HIP_MEMORY_SCOPE_AGENT);
    while (__hip_atomic_load(bar, __ATOMIC_RELAXED, __HIP_MEMORY_SCOPE_AGENT) < target)
      __builtin_amdgcn_s_sleep(2);
    __threadfence();   // acquire: invalidate so we see other blocks' writes
  }
  __syncthreads();
}

// ---------------------------------------------------------------------------
// Persistent encoder GRU: all 48 steps, both directions, one dispatch.
// 256 blocks x 512 threads. Block bid: dir = bid>>7, owns j0 = (bid&127)*8,
// i.e. output cols [j0, j0+8) and weight rows {j, 1024+j, 2048+j}.
// State ht is transposed [buf][dir][k][b] (lane=b coalesced), double-buffered
// -> ONE grid barrier per step. gh stays block-local in LDS.
// Weight reads are wave-uniform (readfirstlane) -> scalar path, L2-resident.
// ---------------------------------------------------------------------------
__global__ __launch_bounds__(512) void enc_gru_persistent(
    const float* __restrict__ gx_f, const float* __restrict__ gx_b,
    const float* __restrict__ Wh_f, const float* __restrict__ Wh_b,
    const float* __restrict__ bh_f, const float* __restrict__ bh_b,
    float* __restrict__ ht,          // [2][2][1024][64] fp32, buf0 zeroed
    float* __restrict__ enc,         // (B,S,2H)
    float* __restrict__ hcat,        // (B,2H)
    int* __restrict__ bar)
{
  __shared__ float gh_l[3][8][64];
  const int tid = threadIdx.x;
  const int bid = blockIdx.x;
  const int dir = bid >> 7;
  const int j0 = (bid & 127) * 8;
  const float* gx = dir ? gx_b : gx_f;
  const float* Wh = dir ? Wh_b : Wh_f;
  const float* bh = dir ? bh_b : bh_f;
  const int lane = tid & 63;
  const int wv = __builtin_amdgcn_readfirstlane(tid >> 6);  // wave id 0..7 (uniform)
  const int j = j0 + wv;                                     // this wave's output col
  const float* w0 = Wh + (size_t)j * 1024;
  const float* w1 = Wh + (size_t)(1024 + j) * 1024;
  const float* w2 = Wh + (size_t)(2048 + j) * 1024;

  // P2 mapping: thread -> (b, jl)
  const int b2 = tid & 63, jl2 = tid >> 6;
  const int jj2 = j0 + jl2;
  const float bh0 = bh[jj2], bh1 = bh[1024 + jj2], bh2 = bh[2048 + jj2];

  for (int s = 0; s < SS; s++) {
    const int cur = s & 1;
    // ---- P1: gh rows {j,1024+j,2048+j} for all 64 batches (lane=b) ----
    float a0 = 0.f, a1 = 0.f, a2 = 0.f;
    if (s) {
      const float* hb = ht + ((size_t)(cur * 2 + dir) * 1024) * 64 + lane;
#pragma unroll 2
      for (int k = 0; k < 1024; k += 8) {
        float hv[8];
#pragma unroll
        for (int i = 0; i < 8; i++) hv[i] = hb[(size_t)(k + i) * 64];
#pragma unroll
        for (int i = 0; i < 8; i++) {
          a0 = fmaf(w0[k + i], hv[i], a0);
          a1 = fmaf(w1[k + i], hv[i], a1);
          a2 = fmaf(w2[k + i], hv[i], a2);
        }
      }
    }
    gh_l[0][wv][lane] = a0;
    gh_l[1][wv][lane] = a1;
    gh_l[2][wv][lane] = a2;
    __syncthreads();

    // ---- P2: GRU elementwise for own 8 cols x 64 batches ----
    const int so = dir ? (SS - 1 - s) : s;
    const float* gxr = gx + ((size_t)so * BB + b2) * 3072 + jj2;
    float hr = gh_l[0][jl2][b2] + bh0;
    float hz = gh_l[1][jl2][b2] + bh1;
    float hn = gh_l[2][jl2][b2] + bh2;
    float rg = sigmoidf_(gxr[0] + hr);
    float zg = sigmoidf_(gxr[1024] + hz);
    float ng = tanhf(gxr[2048] + rg * hn);
    float hprev = ht[((size_t)(cur * 2 + dir) * 1024 + jj2) * 64 + b2];
    float hnew = (1.f - zg) * ng + zg * hprev;
    ht[((size_t)((cur ^ 1) * 2 + dir) * 1024 + jj2) * 64 + b2] = hnew;
    enc[((size_t)b2 * SS + so) * 2048 + dir * 1024 + jj2] = hnew;
    if (s == SS - 1) hcat[b2 * 2048 + dir * 1024 + jj2] = hnew;

    if (s + 1 < SS) gbar(bar, (s + 1) * NBLK_E);
  }
}

// hidden = tanh(sum_p hp + b_fc)
__global__ __launch_bounds__(256) void combine_hidden(
    const float* __restrict__ hp, const float* __restrict__ b_fc,
    float* __restrict__ h_dec)
{
  int idx = blockIdx.x * 256 + threadIdx.x;  // B*H = 65536
  int j = idx & 1023;
  const int P = BB * HH;
  h_dec[idx] = tanhf(hp[idx] + hp[P + idx] + hp[2 * P + idx] + hp[3 * P + idx] + b_fc[j]);
}

// Build Wdh_cat (4096x1024): rows 0..3071 = Wh_d; rows 3072..4095 = W_attn[:, :1024]
__global__ __launch_bounds__(256) void build_wdh(
    const float* __restrict__ Wh_d, const float* __restrict__ W_attn,
    float* __restrict__ Wcat)
{
  int i = blockIdx.x * 256 + threadIdx.x;   // 4096*256 float4 slots
  int r = i >> 8, c4 = (i & 255) * 4;
  float4 v;
  if (r < 3072) v = *(const float4*)(Wh_d + (size_t)r * 1024 + c4);
  else          v = *(const float4*)(W_attn + (size_t)(r - 3072) * 3072 + c4);
  *(float4*)(Wcat + (size_t)r * 1024 + c4) = v;
}

// ---------------------------------------------------------------------------
// Attention step. dpp now lives in cols 3072..4095 of the fused ghdp_cat
// (4 split-K partials, stride BB*4096).
// ---------------------------------------------------------------------------
__global__ __launch_bounds__(256) void attn_step(
    const float* __restrict__ ghdpc,      // (4, B, 4096) fused ghdp|dpp partials
    const float* __restrict__ enc_proj,   // (B,S,H)
    const float* __restrict__ v_attn,
    const float* __restrict__ enc,        // (B,S,2H)
    const int* __restrict__ src,
    const int* __restrict__ trg,
    const float* __restrict__ emb_dec,
    int t,
    float* __restrict__ dec_in,           // (B, E+2H)
    bf16* __restrict__ feat)              // rows t*B.., ld 3584
{
  __shared__ float dp[1024];
  __shared__ float sc[SS];
  __shared__ float aw[SS];
  const int b = blockIdx.x;
  const int tid = threadIdx.x;
  const int PG = BB * 4096;
  for (int jj = tid; jj < 1024; jj += 256) {
    int base = b * 4096 + 3072 + jj;
    dp[jj] = ghdpc[base] + ghdpc[PG + base] + ghdpc[2 * PG + base] + ghdpc[3 * PG + base];
  }
  __syncthreads();

  const int lane = tid & 63, w = tid >> 6;
  for (int s = w; s < SS; s += 4) {
    float p = 0.f;
    const float* ep = enc_proj + ((size_t)b * SS + s) * HH;
    for (int jj = lane; jj < 1024; jj += 64)
      p += tanhf(dp[jj] + ep[jj]) * v_attn[jj];
#pragma unroll
    for (int off = 32; off; off >>= 1) p += __shfl_down(p, off);
    if (lane == 0) sc[s] = p;
  }
  __syncthreads();

  if (tid < 64) {
    float v = -3.0e38f;
    if (tid < SS) v = (src[tid * BB + b] != 1) ? sc[tid] : -1.0e10f;
    float mx = v;
#pragma unroll
    for (int off = 32; off; off >>= 1) mx = fmaxf(mx, __shfl_xor(mx, off));
    float e = (tid < SS) ? expf(v - mx) : 0.f;
    float sum = e;
#pragma unroll
    for (int off = 32; off; off >>= 1) sum += __shfl_xor(sum, off);
    if (tid < SS) aw[tid] = e / sum;
  }
  __syncthreads();

  bf16* frow = feat + ((size_t)t * BB + b) * 3584;
  for (int k = tid; k < 2048; k += 256) {
    float acc = 0.f;
    const float* er = enc + ((size_t)b * SS) * 2048 + k;
#pragma unroll 4
    for (int s = 0; s < SS; s++) acc += aw[s] * er[(size_t)s * 2048];
    dec_in[b * 2560 + 512 + k] = acc;
    frow[1024 + k] = __float2bfloat16(acc);
  }
  const int tok = trg[t * BB + b];
  for (int e = tid; e < 512; e += 256) {
    float ev = emb_dec[(size_t)tok * EE + e];
    dec_in[b * 2560 + e] = ev;
    frow[3072 + e] = __float2bfloat16(ev);
  }
}

// Decoder GRU elementwise (gh partials from the fused 4096-wide buffer).
__global__ __launch_bounds__(256) void gru_dec(
    const float* __restrict__ gxp, const float* __restrict__ ghp,
    const float* __restrict__ bi, const float* __restrict__ bh,
    float* __restrict__ h, bf16* __restrict__ feat, int t)
{
  int idx = blockIdx.x * 256 + threadIdx.x;   // B*H = 65536
  int b = idx >> 10, j = idx & 1023;
  const int xb = b * 3072 + j;
  const int PX = BB * 3072;
  const int gb = b * 4096 + j;
  const int PG = BB * 4096;
  float xr = gxp[xb] + gxp[PX + xb] + gxp[2 * PX + xb] + gxp[3 * PX + xb] + bi[j];
  float xz = gxp[xb + 1024] + gxp[PX + xb + 1024] + gxp[2 * PX + xb + 1024] + gxp[3 * PX + xb + 1024] + bi[1024 + j];
  float xn = gxp[xb + 2048] + gxp[PX + xb + 2048] + gxp[2 * PX + xb + 2048] + gxp[3 * PX + xb + 2048] + bi[2048 + j];
  float hr = ghp[gb] + ghp[PG + gb] + ghp[2 * PG + gb] + ghp[3 * PG + gb] + bh[j];
  float hz = ghp[gb + 1024] + ghp[PG + gb + 1024] + ghp[2 * PG + gb + 1024] + ghp[3 * PG + gb + 1024] + bh[1024 + j];
  float hn = ghp[gb + 2048] + ghp[PG + gb + 2048] + ghp[2 * PG + gb + 2048] + ghp[3 * PG + gb + 2048] + bh[2048 + j];
  float rg = sigmoidf_(xr + hr);
  float zg = sigmoidf_(xz + hz);
  float ng = tanhf(xn + rg * hn);
  float hprev = h[idx];
  float hnew = (1.f - zg) * ng + zg * hprev;
  h[idx] = hnew;
  feat[((size_t)t * BB + b) * 3584 + j] = __float2bfloat16(hnew);
}

// ---------------------------------------------------------------------------
extern "C" void kernel_launch(void* const* d_in, const int* in_sizes, int n_in,
                              void* d_out, int out_size, void* d_ws, size_t ws_size,
                              hipStream_t stream)
{
  const int* src = (const int*)d_in[0];
  const int* trg = (const int*)d_in[1];
  const float* emb_enc = (const float*)d_in[2];
  const float* Wi_f = (const float*)d_in[3];
  const float* Wh_f = (const float*)d_in[4];
  const float* bi_f = (const float*)d_in[5];
  const float* bh_f = (const float*)d_in[6];
  const float* Wi_b = (const float*)d_in[7];
  const float* Wh_b = (const float*)d_in[8];
  const float* bi_b = (const float*)d_in[9];
  const float* bh_b = (const float*)d_in[10];
  const float* W_fc = (const float*)d_in[11];
  const float* b_fc = (const float*)d_in[12];
  const float* W_attn = (const float*)d_in[13];
  const float* b_attn = (const float*)d_in[14];
  const float* v_attn = (const float*)d_in[15];
  const float* emb_dec = (const float*)d_in[16];
  const float* Wi_d = (const float*)d_in[17];
  const float* Wh_d = (const float*)d_in[18];
  const float* bi_d = (const float*)d_in[19];
  const float* bh_d = (const float*)d_in[20];
  const float* W_out = (const float*)d_in[21];
  const float* b_out = (const float*)d_in[22];
  float* out = (float*)d_out;

  // workspace layout (~122 MB total)
  size_t off = 0;
  auto alloc = [&](size_t bytes) {
    void* r = (char*)d_ws + off;
    off += (bytes + 255) & ~(size_t)255;
    return r;
  };
  bf16* emb_bf   = (bf16*)alloc((size_t)SS * BB * EE * 2);
  float* gx_f    = (float*)alloc((size_t)SS * BB * 3072 * 4);
  float* gx_b    = (float*)alloc((size_t)SS * BB * 3072 * 4);
  float* ht      = (float*)alloc((size_t)2 * 2 * 1024 * 64 * 4);
  float* enc     = (float*)alloc((size_t)BB * SS * 2048 * 4);
  float* hcat    = (float*)alloc((size_t)BB * 2048 * 4);
  float* hp      = (float*)alloc((size_t)4 * BB * HH * 4);
  float* h_dec   = (float*)alloc((size_t)BB * HH * 4);
  float* enc_proj= (float*)alloc((size_t)BB * SS * HH * 4);
  float* dec_in  = (float*)alloc((size_t)BB * 2560 * 4);
  float* gxdp    = (float*)alloc((size_t)4 * BB * 3072 * 4);
  float* ghdpc   = (float*)alloc((size_t)4 * BB * 4096 * 4);
  float* Wdh_cat = (float*)alloc((size_t)4096 * 1024 * 4);
  bf16* feat     = (bf16*)alloc((size_t)2048 * 3584 * 2);  // padded to M=2048
  int* bar       = (int*)alloc(256);

  hipMemsetAsync(ht, 0, (size_t)2 * 1024 * 64 * 4, stream);   // buf0, both dirs
  hipMemsetAsync(bar, 0, 256, stream);
  hipMemsetAsync(d_out, 0, (size_t)BB * VV * 4, stream);      // output row t=0

  // --- encoder input GEMMs (MFMA): gx = emb @ Wi^T + bi  (3072x3072xK=512)
  embed_src<<<768, 256, 0, stream>>>(src, emb_enc, emb_bf);
  gemm_mfma<<<dim3(24, 24), 256, 0, stream>>>(emb_bf, 512, Wi_f, 512, bi_f, gx_f, 3072, 512, 3072);
  gemm_mfma<<<dim3(24, 24), 256, 0, stream>>>(emb_bf, 512, Wi_b, 512, bi_b, gx_b, 3072, 512, 3072);
  build_wdh<<<4096, 256, 0, stream>>>(Wh_d, W_attn, Wdh_cat);

  // --- encoder recurrence: ONE persistent kernel (48 steps, fwd+bwd)
  enc_gru_persistent<<<NBLK_E, 512, 0, stream>>>(gx_f, gx_b, Wh_f, Wh_b, bh_f, bh_b,
                                                 ht, enc, hcat, bar);

  // --- hidden = tanh([hf,hb] @ W_fc^T + b_fc)
  gemm64<<<dim3(16, 1, 4), 256, 0, stream>>>(hcat, 2048, W_fc, 2048, nullptr, hp, (long long)BB * HH, 1024, 64, 512);
  combine_hidden<<<256, 256, 0, stream>>>(hp, b_fc, h_dec);

  // --- step-invariant attention precompute: enc_proj = enc @ W_attn[:,H:]^T + b_attn
  gemm64<<<dim3(16, 48, 1), 256, 0, stream>>>(enc, 2048, W_attn + 1024, 3072, b_attn, enc_proj, 0, 1024, 3072, 2048);

  // --- decoder recurrence (31 steps, 4 kernels/step); output projection deferred
  for (int t = 0; t < TT - 1; t++) {
    // fused [ghdp | dpp] = h_dec @ [Wh_d ; W_attn_h]^T  (N=4096, K=1024, split-K 4)
    gemm64<<<dim3(64, 1, 4), 256, 0, stream>>>(h_dec, 1024, Wdh_cat, 1024, nullptr, ghdpc, (long long)BB * 4096, 4096, 64, 256);
    attn_step<<<64, 256, 0, stream>>>(ghdpc, enc_proj, v_attn, enc, src, trg, emb_dec, t, dec_in, feat);
    gemm64<<<dim3(48, 1, 4), 256, 0, stream>>>(dec_in, 2560, Wi_d, 2560, nullptr, gxdp, (long long)BB * 3072, 3072, 64, 640);
    gru_dec<<<256, 256, 0, stream>>>(gxdp, ghdpc, bi_d, bh_d, h_dec, feat, t);
  }

  // --- batched output projection: (31*64=1984) x 32000 x 3584, fp32 out
  // grid: x = m-tiles (16, fast) so W_out n-panels are shared by adjacent blocks
  gemm_mfma<<<dim3(16, 250), 256, 0, stream>>>(feat, 3584, W_out, 3584, b_out,
                                               out + (size_t)BB * VV, VV, 3584, 1984);
}